// Round 9
// baseline (39.813 us; speedup 1.0000x reference)
//
#include <hip/hip_runtime.h>
#include <math.h>

namespace {

constexpr int   kBd    = 64;
constexpr int   kA     = 3;
constexpr int   kC     = 20;
constexpr int   kG     = 76;
constexpr int   kGG    = kG * kG;              // 5776 (multiple of 4)
constexpr int   kCH    = 5 + kC;               // 25
constexpr int   kNCell = kBd * kA * kGG;       // 1,108,992
constexpr int   kNC4   = kNCell / 4;           // 277,248
constexpr int   kBlk   = 256;
constexpr int   kGrid  = kNC4 / kBlk;          // 1083 exact
constexpr float kEps   = 1e-7f;
constexpr float kInvG  = 1.0f / (float)kG;
constexpr float kPiO2  = 1.57079632679f;

// ws: part[b*8 + s], s=0..4 : {objc, noobj, coord, cls, n_obj} per block
constexpr int kPartStride = 8;   // 32 B per block

__device__ __forceinline__ float softplus_fast(float x) {
  // log(1+exp(x)) via hw v_exp/v_log; log argument in (1,2] -> accurate
  return fmaxf(x, 0.0f) + __logf(1.0f + __expf(-fabsf(x)));
}
__device__ __forceinline__ float sigmoidf(float x) {
  return 1.0f / (1.0f + __expf(-x));
}
__device__ __forceinline__ float clamp01(float x) {
  return fminf(fmaxf(x, 0.0f), 1.0f);
}

// atan(num/den) for num,den > 0: one fast divide + deg-9 minimax poly
// (|err| ~1e-5; loss-level error << 0.159 threshold).
__device__ __forceinline__ float atan_ratio(float num, float den) {
  const float z  = __fdividef(fminf(num, den), fmaxf(num, den));
  const float z2 = z * z;
  float p = 0.0208351f;
  p = fmaf(p, z2, -0.0851330f);
  p = fmaf(p, z2,  0.1801410f);
  p = fmaf(p, z2, -0.3302995f);
  p = fmaf(p, z2,  0.9998660f);
  const float a = z * p;
  return (num > den) ? (kPiO2 - a) : a;
}

// CIoU from register-held prediction/target scalars.
__device__ __forceinline__ float ciou_vals(
    float px, float py, float pwv, float phv,
    float tx, float ty, float tw, float th,
    float fgx, float fgy, float aw, float ah) {
  const float pcx = (fgx + sigmoidf(px)) * kInvG;
  const float pcy = (fgy + sigmoidf(py)) * kInvG;
  const float pw  = __expf(pwv) * aw;
  const float ph  = __expf(phv) * ah;
  const float x1p = clamp01(pcx - 0.5f * pw);
  const float y1p = clamp01(pcy - 0.5f * ph);
  const float x2p = clamp01(pcx + 0.5f * pw);
  const float y2p = clamp01(pcy + 0.5f * ph);

  const float tcx = (fgx + tx) * kInvG;
  const float tcy = (fgy + ty) * kInvG;
  const float twv = __expf(tw) * aw;
  const float thv = __expf(th) * ah;
  const float x1t = clamp01(tcx - 0.5f * twv);
  const float y1t = clamp01(tcy - 0.5f * thv);
  const float x2t = clamp01(tcx + 0.5f * twv);
  const float y2t = clamp01(tcy + 0.5f * thv);

  const float iw     = fmaxf(fminf(x2p, x2t) - fmaxf(x1p, x1t), 0.0f);
  const float ih     = fmaxf(fminf(y2p, y2t) - fmaxf(y1p, y1t), 0.0f);
  const float inter  = iw * ih;
  const float area_p = fmaxf(x2p - x1p, 0.0f) * fmaxf(y2p - y1p, 0.0f);
  const float area_t = fmaxf(x2t - x1t, 0.0f) * fmaxf(y2t - y1t, 0.0f);
  const float uni    = area_p + area_t - inter + kEps;
  const float iou    = __fdividef(inter, uni);
  const float dx     = (x1p + x2p - x1t - x2t) * 0.5f;
  const float dy     = (y1p + y2p - y1t - y2t) * 0.5f;
  const float rho2   = dx * dx + dy * dy;
  const float enw    = fmaxf(fmaxf(x2p, x2t) - fminf(x1p, x1t), kEps);
  const float enh    = fmaxf(fmaxf(y2p, y2t) - fminf(y1p, y1t), kEps);
  const float c2     = enw * enw + enh * enh;
  const float wp     = fmaxf(x2p - x1p, kEps);
  const float hp     = fmaxf(y2p - y1p, kEps);
  const float wt     = fmaxf(x2t - x1t, kEps);
  const float ht     = fmaxf(y2t - y1t, kEps);
  const float k4pi2  = 4.0f / (float)(M_PI * M_PI);
  const float dat    = atan_ratio(wt, ht) - atan_ratio(wp, hp);
  const float v      = k4pi2 * dat * dat;
  const float alpha  = __fdividef(v, 1.0f - iou + v + kEps);
  const float ciou   = iou - __fdividef(rho2, c2 + kEps) - alpha * v;
  return 1.0f - ciou;
}

// Deterministic block reduction of N floats; thread 0 writes out[0..N).
template <int N, int BLK>
__device__ __forceinline__ void block_reduceN(float r[N], float* out) {
  #pragma unroll
  for (int off = 32; off > 0; off >>= 1) {
    #pragma unroll
    for (int s = 0; s < N; ++s) r[s] += __shfl_down(r[s], off, 64);
  }
  __shared__ float red[BLK / 64][N];
  const int lane = threadIdx.x & 63;
  const int wid  = threadIdx.x >> 6;
  if (lane == 0) {
    #pragma unroll
    for (int s = 0; s < N; ++s) red[wid][s] = r[s];
  }
  __syncthreads();
  if (threadIdx.x == 0) {
    #pragma unroll
    for (int s = 0; s < N; ++s) {
      float a = red[0][s];
      #pragma unroll
      for (int w = 1; w < BLK / 64; ++w) a += red[w][s];
      out[s] = a;
    }
  }
}

// Dense-hybrid single pass: every thread streams targets+conf for its 4
// cells; only nibbles containing an obj cell (18.5% of threads) read the
// box+class float4s and do the heavy math inline. No LDS lists, no scans,
// no barriers before the reduce, no global atomics.
__global__ __launch_bounds__(kBlk) void yolo_dense(
    const float* __restrict__ preds,
    const float* __restrict__ tgts,
    const float* __restrict__ anchors,
    float* __restrict__ part) {
  const int b    = blockIdx.x;
  const int q    = b * kBlk + threadIdx.x;   // grid is exact
  const int cell = q * 4;
  const int ba   = cell / kGG;
  const int j0   = cell - ba * kGG;

  // targets for 4 cells: 5 aligned float4
  union { float4 v[5]; float f[20]; } T;
  const float4* tb = (const float4*)(tgts + (size_t)cell * 5);
  #pragma unroll
  for (int i = 0; i < 5; ++i) T.v[i] = tb[i];

  const float* pb = preds + (size_t)ba * kCH * kGG + j0;

  // conf channel (ch 4) for the 4 cells
  const float4 P4 = *(const float4*)(pb + (size_t)4 * kGG);
  const float p4a[4] = { P4.x, P4.y, P4.z, P4.w };

  float r[5] = {0.f, 0.f, 0.f, 0.f, 0.f};  // objc, noobj, coord, cls, n_obj
  unsigned msk = 0u;

  #pragma unroll
  for (int i = 0; i < 4; ++i) {
    const bool obj = T.f[i * 5 + 4] > 0.0f;
    const float sp = softplus_fast(p4a[i]);
    if (obj) {
      r[0] += sp - p4a[i];   // t==1: softplus(-x) = softplus(x) - x
      r[4] += 1.0f;
      msk |= (1u << i);
    } else {
      r[1] += sp;            // -log1p(-sigmoid(x)) = softplus(x)
    }
  }

  if (msk) {
    const int a = ba % kA;
    const float aw = anchors[2 * a]     * kInvG;
    const float ah = anchors[2 * a + 1] * kInvG;

    // box channels 0..3 for the nibble (4 coalesced float4 among active lanes)
    const float4 B0 = *(const float4*)(pb + (size_t)0 * kGG);
    const float4 B1 = *(const float4*)(pb + (size_t)1 * kGG);
    const float4 B2 = *(const float4*)(pb + (size_t)2 * kGG);
    const float4 B3 = *(const float4*)(pb + (size_t)3 * kGG);
    const float b0a[4] = {B0.x, B0.y, B0.z, B0.w};
    const float b1a[4] = {B1.x, B1.y, B1.z, B1.w};
    const float b2a[4] = {B2.x, B2.y, B2.z, B2.w};
    const float b3a[4] = {B3.x, B3.y, B3.z, B3.w};

    #pragma unroll
    for (int i = 0; i < 4; ++i) {
      if ((msk >> i) & 1u) {
        const int j  = j0 + i;
        const int gy = j / kG;
        const int gx = j - gy * kG;
        r[2] += ciou_vals(b0a[i], b1a[i], b2a[i], b3a[i],
                          T.f[i * 5 + 0], T.f[i * 5 + 1],
                          T.f[i * 5 + 2], T.f[i * 5 + 3],
                          (float)gx, (float)gy, aw, ah);
      }
    }

    // class channels: 20 coalesced float4 reads, masked softplus accumulate
    float cacc = 0.0f;
    #pragma unroll
    for (int c = 0; c < kC; ++c) {
      const float4 v = *(const float4*)(pb + (size_t)(5 + c) * kGG);
      cacc += (msk & 1u) ? softplus_fast(-v.x) : 0.0f;
      cacc += (msk & 2u) ? softplus_fast(-v.y) : 0.0f;
      cacc += (msk & 4u) ? softplus_fast(-v.z) : 0.0f;
      cacc += (msk & 8u) ? softplus_fast(-v.w) : 0.0f;
    }
    r[3] = cacc;
  }

  block_reduceN<5, kBlk>(r, part + (size_t)b * kPartStride);
}

__global__ __launch_bounds__(256) void yolo_finish(
    const float* __restrict__ part, float* __restrict__ out) {
  float r[5] = {0.f, 0.f, 0.f, 0.f, 0.f};
  for (int i = threadIdx.x; i < kGrid; i += 256) {
    const float* pi = part + (size_t)i * kPartStride;
    #pragma unroll
    for (int s = 0; s < 5; ++s) r[s] += pi[s];
  }
  __shared__ float outbuf[5];
  block_reduceN<5, 256>(r, outbuf);
  __syncthreads();
  if (threadIdx.x == 0) {
    const float objc    = outbuf[0];
    const float noobj   = outbuf[1];
    const float coord   = outbuf[2];
    const float cls     = outbuf[3];
    const float n_obj   = outbuf[4];
    const float n_noobj = (float)kNCell - n_obj;

    const float coord_loss = (n_obj > 0.f)   ? coord / fmaxf(n_obj, 1.f)   : 0.f;
    const float obj_loss   = (n_obj > 0.f)   ? objc  / fmaxf(n_obj, 1.f)   : 0.f;
    const float noobj_loss = (n_noobj > 0.f) ? noobj / fmaxf(n_noobj, 1.f) : 0.f;
    const float class_loss = (n_obj > 0.f)   ? cls / fmaxf(n_obj * (float)kC, 1.f) : 0.f;

    out[0] = 10.0f * coord_loss + 1.0f * obj_loss + 0.5f * noobj_loss + class_loss;
  }
}

}  // namespace

extern "C" void kernel_launch(void* const* d_in, const int* in_sizes, int n_in,
                              void* d_out, int out_size, void* d_ws, size_t ws_size,
                              hipStream_t stream) {
  const float* preds   = (const float*)d_in[0];
  const float* tgts    = (const float*)d_in[1];
  const float* anchors = (const float*)d_in[2];
  float* out  = (float*)d_out;
  float* part = (float*)d_ws;   // kGrid * 8 floats ~ 35 KB

  yolo_dense<<<kGrid, kBlk, 0, stream>>>(preds, tgts, anchors, part);
  yolo_finish<<<1, 256, 0, stream>>>(part, out);
}

// Round 10
// 26.898 us; speedup vs baseline: 1.4801x; 1.4801x over previous
//
#include <hip/hip_runtime.h>
#include <math.h>

namespace {

constexpr int   kBd    = 64;
constexpr int   kA     = 3;
constexpr int   kC     = 20;
constexpr int   kG     = 76;
constexpr int   kGG    = kG * kG;              // 5776
constexpr int   kCH    = 5 + kC;               // 25
constexpr int   kNCell = kBd * kA * kGG;       // 1,108,992
constexpr int   kNC4   = kNCell / 4;           // 277,248
constexpr int   kBlk   = 256;
constexpr int   kGrid  = kNC4 / kBlk;          // 1083 exact
constexpr int   kCellsPerBlk = kBlk * 4;       // 1024
constexpr float kEps   = 1e-7f;
constexpr float kInvG  = 1.0f / (float)kG;
constexpr float kPiO2  = 1.57079632679f;

// ws layout (32-bit words), plain stores only, visibility via kernel boundary:
//  part[b*8 + s], s=0..4 : float {objc, noobj, coord, cls, n_obj} per block
constexpr int kPartStride = 8;   // 32 B per block

__device__ __forceinline__ float softplus_fast(float x) {
  // log(1+exp(x)) via hw v_exp/v_log; log argument in (1,2] -> accurate
  return fmaxf(x, 0.0f) + __logf(1.0f + __expf(-fabsf(x)));
}
__device__ __forceinline__ float sigmoidf(float x) {
  return 1.0f / (1.0f + __expf(-x));
}
__device__ __forceinline__ float clamp01(float x) {
  return fminf(fmaxf(x, 0.0f), 1.0f);
}

// atan(num/den) for num,den > 0: one fast divide + deg-9 minimax poly
// (|err| ~1e-5; loss-level error << 0.159 threshold).
__device__ __forceinline__ float atan_ratio(float num, float den) {
  const float z  = __fdividef(fminf(num, den), fmaxf(num, den));
  const float z2 = z * z;
  float p = 0.0208351f;
  p = fmaf(p, z2, -0.0851330f);
  p = fmaf(p, z2,  0.1801410f);
  p = fmaf(p, z2, -0.3302995f);
  p = fmaf(p, z2,  0.9998660f);
  const float a = z * p;
  return (num > den) ? (kPiO2 - a) : a;
}

// CIoU for one obj cell (box channels 0..3 + LDS-held targets).
__device__ __forceinline__ float ciou_cell(
    int cell, float tx, float ty, float tw, float th,
    const float* __restrict__ preds, const float* __restrict__ anchors) {
  const int ba = cell / kGG;
  const int j  = cell - ba * kGG;
  const int a  = ba % kA;
  const int gy = j / kG;
  const int gx = j - gy * kG;
  const float fgx = (float)gx, fgy = (float)gy;

  const float aw = anchors[2 * a]     * kInvG;
  const float ah = anchors[2 * a + 1] * kInvG;

  const float* pb = preds + (size_t)ba * kCH * kGG + j;
  const float px  = pb[0];
  const float py  = pb[(size_t)1 * kGG];
  const float pwv = pb[(size_t)2 * kGG];
  const float phv = pb[(size_t)3 * kGG];

  const float pcx = (fgx + sigmoidf(px)) * kInvG;
  const float pcy = (fgy + sigmoidf(py)) * kInvG;
  const float pw  = __expf(pwv) * aw;
  const float ph  = __expf(phv) * ah;
  const float x1p = clamp01(pcx - 0.5f * pw);
  const float y1p = clamp01(pcy - 0.5f * ph);
  const float x2p = clamp01(pcx + 0.5f * pw);
  const float y2p = clamp01(pcy + 0.5f * ph);

  const float tcx = (fgx + tx) * kInvG;
  const float tcy = (fgy + ty) * kInvG;
  const float twv = __expf(tw) * aw;
  const float thv = __expf(th) * ah;
  const float x1t = clamp01(tcx - 0.5f * twv);
  const float y1t = clamp01(tcy - 0.5f * thv);
  const float x2t = clamp01(tcx + 0.5f * twv);
  const float y2t = clamp01(tcy + 0.5f * thv);

  const float iw     = fmaxf(fminf(x2p, x2t) - fmaxf(x1p, x1t), 0.0f);
  const float ih     = fmaxf(fminf(y2p, y2t) - fmaxf(y1p, y1t), 0.0f);
  const float inter  = iw * ih;
  const float area_p = fmaxf(x2p - x1p, 0.0f) * fmaxf(y2p - y1p, 0.0f);
  const float area_t = fmaxf(x2t - x1t, 0.0f) * fmaxf(y2t - y1t, 0.0f);
  const float uni    = area_p + area_t - inter + kEps;
  const float iou    = __fdividef(inter, uni);
  const float dx     = (x1p + x2p - x1t - x2t) * 0.5f;
  const float dy     = (y1p + y2p - y1t - y2t) * 0.5f;
  const float rho2   = dx * dx + dy * dy;
  const float enw    = fmaxf(fmaxf(x2p, x2t) - fminf(x1p, x1t), kEps);
  const float enh    = fmaxf(fmaxf(y2p, y2t) - fminf(y1p, y1t), kEps);
  const float c2     = enw * enw + enh * enh;
  const float wp     = fmaxf(x2p - x1p, kEps);
  const float hp     = fmaxf(y2p - y1p, kEps);
  const float wt     = fmaxf(x2t - x1t, kEps);
  const float ht     = fmaxf(y2t - y1t, kEps);
  const float k4pi2  = 4.0f / (float)(M_PI * M_PI);
  const float dat    = atan_ratio(wt, ht) - atan_ratio(wp, hp);
  const float v      = k4pi2 * dat * dat;
  const float alpha  = __fdividef(v, 1.0f - iou + v + kEps);
  const float ciou   = iou - __fdividef(rho2, c2 + kEps) - alpha * v;
  return 1.0f - ciou;
}

// Deterministic block reduction of N floats; thread 0 writes out[0..N).
template <int N, int BLK>
__device__ __forceinline__ void block_reduceN(float r[N], float* out) {
  #pragma unroll
  for (int off = 32; off > 0; off >>= 1) {
    #pragma unroll
    for (int s = 0; s < N; ++s) r[s] += __shfl_down(r[s], off, 64);
  }
  __shared__ float red[BLK / 64][N];
  const int lane = threadIdx.x & 63;
  const int wid  = threadIdx.x >> 6;
  if (lane == 0) {
    #pragma unroll
    for (int s = 0; s < N; ++s) red[wid][s] = r[s];
  }
  __syncthreads();
  if (threadIdx.x == 0) {
    #pragma unroll
    for (int s = 0; s < N; ++s) {
      float a = red[0][s];
      #pragma unroll
      for (int w = 1; w < BLK / 64; ++w) a += red[w][s];
      out[s] = a;
    }
  }
}

// Fused: stream targets+conf, block-local compaction to LDS, then flat
// work-item heavy phase: [0,total) CIoU items + [0,total*4) class items
// (5 channels each). Plain-store per-block partials; no atomics, no fences.
__global__ __launch_bounds__(kBlk) void yolo_fused(
    const float* __restrict__ preds,
    const float* __restrict__ tgts,
    const float* __restrict__ anchors,
    float* __restrict__ part) {
  __shared__ int    s_list[kCellsPerBlk];   // 4 KB
  __shared__ float4 s_tgt[kCellsPerBlk];    // 16 KB
  __shared__ int    s_wtot[kBlk / 64];

  const int b    = blockIdx.x;
  const int q    = b * kBlk + threadIdx.x;   // grid is exact
  const int cell = q * 4;
  const int ba   = cell / kGG;
  const int j0   = cell - ba * kGG;

  // targets for 4 cells: 5 aligned float4
  union { float4 v[5]; float f[20]; } T;
  const float4* tb = (const float4*)(tgts + (size_t)cell * 5);
  #pragma unroll
  for (int i = 0; i < 5; ++i) T.v[i] = tb[i];

  // conf channel (ch 4) for the 4 cells
  const float* p4p = preds + (size_t)ba * kCH * kGG + (size_t)4 * kGG + j0;
  const float4 P4 = *(const float4*)p4p;
  const float p4a[4] = { P4.x, P4.y, P4.z, P4.w };

  float r[5] = {0.f, 0.f, 0.f, 0.f, 0.f};  // objc, noobj, coord, cls, n_obj
  unsigned msk = 0u;

  #pragma unroll
  for (int i = 0; i < 4; ++i) {
    const bool obj = T.f[i * 5 + 4] > 0.0f;
    const float sp = softplus_fast(p4a[i]);
    if (obj) {
      r[0] += sp - p4a[i];   // t==1: softplus(-x) = softplus(x) - x
      r[4] += 1.0f;
      msk |= (1u << i);
    } else {
      r[1] += sp;            // -log1p(-sigmoid(x)) = softplus(x)
    }
  }
  const int cnt = __popc(msk);

  // deterministic block-wide exclusive position: wave scan + per-wave totals
  const int lane = threadIdx.x & 63;
  const int wid  = threadIdx.x >> 6;
  int incl = cnt;
  #pragma unroll
  for (int off = 1; off < 64; off <<= 1) {
    const int n = __shfl_up(incl, off, 64);
    if (lane >= off) incl += n;
  }
  const int excl = incl - cnt;

  if (lane == 63) s_wtot[wid] = incl;
  __syncthreads();

  int wbase = 0;
  #pragma unroll
  for (int w = 0; w < kBlk / 64; ++w) wbase += (w < wid) ? s_wtot[w] : 0;
  const int total = s_wtot[0] + s_wtot[1] + s_wtot[2] + s_wtot[3];

  int p = wbase + excl;
  #pragma unroll
  for (int i = 0; i < 4; ++i) {
    if ((msk >> i) & 1u) {
      s_list[p] = cell + i;
      s_tgt[p]  = make_float4(T.f[i * 5 + 0], T.f[i * 5 + 1],
                              T.f[i * 5 + 2], T.f[i * 5 + 3]);
      ++p;
    }
  }
  __syncthreads();

  // heavy phase, flat work items (total ~51 per block):
  //   CIoU: one item per obj cell (threads 0..total-1)
  for (int i = threadIdx.x; i < total; i += kBlk) {
    const float4 t4 = s_tgt[i];
    r[2] += ciou_cell(s_list[i], t4.x, t4.y, t4.z, t4.w, preds, anchors);
  }
  //   class: 4 items per obj cell, 5 channels each (bit-op decomposition)
  const int nwork = total * 4;
  for (int w = threadIdx.x; w < nwork; w += kBlk) {
    const int i = w >> 2;
    const int t = w & 3;
    const int c   = s_list[i];
    const int cba = c / kGG;
    const int cj  = c - cba * kGG;
    const float* cp = preds + (size_t)cba * kCH * kGG + (size_t)(5 + 5 * t) * kGG + cj;
    float cacc = 0.0f;
    #pragma unroll
    for (int k = 0; k < 5; ++k) cacc += softplus_fast(-cp[(size_t)k * kGG]);
    r[3] += cacc;
  }

  block_reduceN<5, kBlk>(r, part + (size_t)b * kPartStride);
}

__global__ __launch_bounds__(256) void yolo_finish(
    const float* __restrict__ part, float* __restrict__ out) {
  float r[5] = {0.f, 0.f, 0.f, 0.f, 0.f};
  for (int i = threadIdx.x; i < kGrid; i += 256) {
    const float* pi = part + (size_t)i * kPartStride;
    #pragma unroll
    for (int s = 0; s < 5; ++s) r[s] += pi[s];
  }
  __shared__ float outbuf[5];
  block_reduceN<5, 256>(r, outbuf);
  __syncthreads();
  if (threadIdx.x == 0) {
    const float objc    = outbuf[0];
    const float noobj   = outbuf[1];
    const float coord   = outbuf[2];
    const float cls     = outbuf[3];
    const float n_obj   = outbuf[4];
    const float n_noobj = (float)kNCell - n_obj;

    const float coord_loss = (n_obj > 0.f)   ? coord / fmaxf(n_obj, 1.f)   : 0.f;
    const float obj_loss   = (n_obj > 0.f)   ? objc  / fmaxf(n_obj, 1.f)   : 0.f;
    const float noobj_loss = (n_noobj > 0.f) ? noobj / fmaxf(n_noobj, 1.f) : 0.f;
    const float class_loss = (n_obj > 0.f)   ? cls / fmaxf(n_obj * (float)kC, 1.f) : 0.f;

    out[0] = 10.0f * coord_loss + 1.0f * obj_loss + 0.5f * noobj_loss + class_loss;
  }
}

}  // namespace

extern "C" void kernel_launch(void* const* d_in, const int* in_sizes, int n_in,
                              void* d_out, int out_size, void* d_ws, size_t ws_size,
                              hipStream_t stream) {
  const float* preds   = (const float*)d_in[0];
  const float* tgts    = (const float*)d_in[1];
  const float* anchors = (const float*)d_in[2];
  float* out  = (float*)d_out;
  float* part = (float*)d_ws;   // kGrid * 8 floats ~ 35 KB

  yolo_fused<<<kGrid, kBlk, 0, stream>>>(preds, tgts, anchors, part);
  yolo_finish<<<1, 256, 0, stream>>>(part, out);
}